// Round 1
// baseline (4865.068 us; speedup 1.0000x reference)
//
#include <hip/hip_runtime.h>
#include <hip/hip_bf16.h>

constexpr int D    = 128;   // d_model
constexpr int HF   = 256;   // ffn / output dim
constexpr int NH   = 4;
constexpr int DH   = 32;
constexpr int NL   = 3;
constexpr int SEQ  = 1024;
constexpr int NB   = 65;    // 64 support + 1 query
constexpr int NTOK = NB * SEQ;   // 66560
constexpr int NSUP = 64 * SEQ;   // 65536
constexpr int NC   = 10;

// ---------------- embedding ----------------
__global__ __launch_bounds__(256) void k_embed(const int* __restrict__ sup,
                                               const int* __restrict__ qry,
                                               const float* __restrict__ emb,
                                               float* __restrict__ x) {
  int64_t i = (int64_t)blockIdx.x * 256 + threadIdx.x;
  int tok_i = (int)(i >> 7);
  int d = (int)(i & 127);
  int t = tok_i < NSUP ? sup[tok_i] : qry[tok_i - NSUP];
  x[i] = emb[t * D + d];
}

// ---------------- GEMM: C[m,n] = sum_k A[m,k]*B[n,k] + bias[n] ----------------
// A row stride = lda (elements); B is [N,K] row-major (weight, stride K); C stride N.
// Tiles: BM=BN=128, BK=32. 256 threads, 8x8 micro-tile per thread.
template<bool RELU>
__global__ __launch_bounds__(256) void k_gemm(const float* __restrict__ A, int lda,
                                              const float* __restrict__ B,
                                              const float* __restrict__ bias,
                                              float* __restrict__ Cm,
                                              int M, int N, int K) {
  constexpr int BK = 32;
  __shared__ float As[BK][132];  // [k][m], pad 4 keeps rows 16B-aligned (528B)
  __shared__ float Bs[BK][132];  // [k][n]
  const int m0 = blockIdx.x * 128;
  const int n0 = blockIdx.y * 128;
  const int tid = threadIdx.x;
  const int tm = tid & 15;   // 16 threads cover m
  const int tn = tid >> 4;   // 16 threads cover n
  float acc[8][8] = {};

  for (int k0 = 0; k0 < K; k0 += BK) {
    __syncthreads();
    #pragma unroll
    for (int it = 0; it < 4; ++it) {
      int idx = tid + it * 256;      // 0..1023
      int r = idx >> 3;              // 0..127
      int c4 = (idx & 7) * 4;        // 0,4,..,28
      float4 va = *(const float4*)(A + (size_t)(m0 + r) * lda + k0 + c4);
      As[c4 + 0][r] = va.x; As[c4 + 1][r] = va.y;
      As[c4 + 2][r] = va.z; As[c4 + 3][r] = va.w;
      float4 vb = *(const float4*)(B + (size_t)(n0 + r) * K + k0 + c4);
      Bs[c4 + 0][r] = vb.x; Bs[c4 + 1][r] = vb.y;
      Bs[c4 + 2][r] = vb.z; Bs[c4 + 3][r] = vb.w;
    }
    __syncthreads();
    #pragma unroll 4
    for (int k = 0; k < BK; ++k) {
      float4 a0 = *(const float4*)&As[k][tm * 4];
      float4 a1 = *(const float4*)&As[k][64 + tm * 4];
      float4 b0 = *(const float4*)&Bs[k][tn * 4];
      float4 b1 = *(const float4*)&Bs[k][64 + tn * 4];
      float a_[8] = {a0.x, a0.y, a0.z, a0.w, a1.x, a1.y, a1.z, a1.w};
      float b_[8] = {b0.x, b0.y, b0.z, b0.w, b1.x, b1.y, b1.z, b1.w};
      #pragma unroll
      for (int i = 0; i < 8; ++i)
        #pragma unroll
        for (int j = 0; j < 8; ++j)
          acc[i][j] += a_[i] * b_[j];
    }
  }

  #pragma unroll
  for (int i = 0; i < 8; ++i) {
    int m = m0 + ((i < 4) ? (tm * 4 + i) : (64 + tm * 4 + i - 4));
    float* crow = Cm + (size_t)m * N + n0;
    #pragma unroll
    for (int half = 0; half < 2; ++half) {
      int nb = half * 64 + tn * 4;
      float4 o;
      o.x = acc[i][half * 4 + 0] + bias[n0 + nb + 0];
      o.y = acc[i][half * 4 + 1] + bias[n0 + nb + 1];
      o.z = acc[i][half * 4 + 2] + bias[n0 + nb + 2];
      o.w = acc[i][half * 4 + 3] + bias[n0 + nb + 3];
      if (RELU) {
        o.x = fmaxf(o.x, 0.f); o.y = fmaxf(o.y, 0.f);
        o.z = fmaxf(o.z, 0.f); o.w = fmaxf(o.w, 0.f);
      }
      *(float4*)(crow + nb) = o;
    }
  }
}

// ---------------- attention (flash-style, fp32), in-place on qkv ----------------
// qkv row layout: [q(128) | k(128) | v(128)], head h owns dims h*32..h*32+31.
// Output o is written back into the q-slot (no other block reads this region).
// grid: (NB*NH, 2); block 256; each thread handles 2 query rows.
__global__ __launch_bounds__(256) void k_attn(float* __restrict__ qkv) {
  const int bh = blockIdx.x;
  const int b = bh >> 2;
  const int h = bh & 3;
  const int tid = threadIdx.x;
  const int row0 = blockIdx.y * 512 + tid;
  const int row1 = row0 + 256;
  __shared__ float Kt[64][DH];
  __shared__ float Vt[64][DH];
  const float kscale = 0.17677669529663687f * 1.4426950408889634f;  // 1/sqrt(32)*log2(e)

  float q0r[DH], q1r[DH], o0[DH] = {}, o1[DH] = {};
  const float* qp0 = qkv + (size_t)(b * SEQ + row0) * 384 + h * DH;
  const float* qp1 = qkv + (size_t)(b * SEQ + row1) * 384 + h * DH;
  #pragma unroll
  for (int c = 0; c < 8; ++c) {
    *(float4*)(q0r + c * 4) = *(const float4*)(qp0 + c * 4);
    *(float4*)(q1r + c * 4) = *(const float4*)(qp1 + c * 4);
  }
  float m0v = -1e30f, m1v = -1e30f, l0 = 0.f, l1 = 0.f;

  for (int kt = 0; kt < SEQ; kt += 64) {
    __syncthreads();
    #pragma unroll
    for (int it = 0; it < 2; ++it) {
      int idx = tid + it * 256;
      int r = idx >> 3;
      int c = (idx & 7) * 4;
      const float* src = qkv + (size_t)(b * SEQ + kt + r) * 384 + 128 + h * DH + c;
      *(float4*)(&Kt[r][c]) = *(const float4*)src;
      *(float4*)(&Vt[r][c]) = *(const float4*)(src + 128);
    }
    __syncthreads();
    #pragma unroll 1
    for (int j = 0; j < 64; ++j) {
      float kr[DH];
      #pragma unroll
      for (int c = 0; c < 8; ++c) *(float4*)(kr + c * 4) = *(const float4*)(&Kt[j][c * 4]);
      float d00 = 0.f, d01 = 0.f, d02 = 0.f, d03 = 0.f;
      float d10 = 0.f, d11 = 0.f, d12 = 0.f, d13 = 0.f;
      #pragma unroll
      for (int d = 0; d < 8; ++d) {
        d00 += q0r[d]      * kr[d];
        d01 += q0r[d + 8]  * kr[d + 8];
        d02 += q0r[d + 16] * kr[d + 16];
        d03 += q0r[d + 24] * kr[d + 24];
        d10 += q1r[d]      * kr[d];
        d11 += q1r[d + 8]  * kr[d + 8];
        d12 += q1r[d + 16] * kr[d + 16];
        d13 += q1r[d + 24] * kr[d + 24];
      }
      float s0 = ((d00 + d01) + (d02 + d03)) * kscale;
      float s1 = ((d10 + d11) + (d12 + d13)) * kscale;
      float nm0 = fmaxf(m0v, s0), nm1 = fmaxf(m1v, s1);
      float c0 = exp2f(m0v - nm0), c1 = exp2f(m1v - nm1);
      float p0 = exp2f(s0 - nm0), p1 = exp2f(s1 - nm1);
      m0v = nm0; m1v = nm1;
      l0 = l0 * c0 + p0;
      l1 = l1 * c1 + p1;
      float vr[DH];
      #pragma unroll
      for (int c = 0; c < 8; ++c) *(float4*)(vr + c * 4) = *(const float4*)(&Vt[j][c * 4]);
      #pragma unroll
      for (int d = 0; d < DH; ++d) {
        o0[d] = o0[d] * c0 + p0 * vr[d];
        o1[d] = o1[d] * c1 + p1 * vr[d];
      }
    }
  }
  float inv0 = 1.f / l0, inv1 = 1.f / l1;
  float* dst0 = qkv + (size_t)(b * SEQ + row0) * 384 + h * DH;
  float* dst1 = qkv + (size_t)(b * SEQ + row1) * 384 + h * DH;
  #pragma unroll
  for (int c = 0; c < 8; ++c) {
    float4 t0, t1;
    t0.x = o0[c*4+0]*inv0; t0.y = o0[c*4+1]*inv0; t0.z = o0[c*4+2]*inv0; t0.w = o0[c*4+3]*inv0;
    t1.x = o1[c*4+0]*inv1; t1.y = o1[c*4+1]*inv1; t1.z = o1[c*4+2]*inv1; t1.w = o1[c*4+3]*inv1;
    *(float4*)(dst0 + c * 4) = t0;
    *(float4*)(dst1 + c * 4) = t1;
  }
}

// ---------------- residual add + LayerNorm (in place on x) ----------------
// x = LN(x + y) * gamma + beta. One wave per row, 2 elems/lane. grid NTOK/4, block 256.
__global__ __launch_bounds__(256) void k_add_ln(float* __restrict__ x,
                                                const float* __restrict__ y,
                                                const float* __restrict__ gamma,
                                                const float* __restrict__ beta) {
  int row = blockIdx.x * 4 + (threadIdx.x >> 6);
  int lane = threadIdx.x & 63;
  float* xr = x + (size_t)row * D;
  const float* yr = y + (size_t)row * D;
  float2 v = *(float2*)(xr + lane * 2);
  float2 w = *(const float2*)(yr + lane * 2);
  float a = v.x + w.x, b = v.y + w.y;
  float sum = a + b;
  #pragma unroll
  for (int off = 32; off; off >>= 1) sum += __shfl_xor(sum, off);
  float mean = sum * (1.f / 128.f);
  float da = a - mean, db = b - mean;
  float vs = da * da + db * db;
  #pragma unroll
  for (int off = 32; off; off >>= 1) vs += __shfl_xor(vs, off);
  float inv = 1.f / sqrtf(vs * (1.f / 128.f) + 1e-5f);
  float2 o;
  o.x = da * inv * gamma[lane * 2 + 0] + beta[lane * 2 + 0];
  o.y = db * inv * gamma[lane * 2 + 1] + beta[lane * 2 + 1];
  *(float2*)(xr + lane * 2) = o;
}

// ---------------- prototype accumulation (hierarchical scatter-mean) ----------------
__global__ __launch_bounds__(256) void k_proto_accum(const float* __restrict__ feat,
                                                     const int* __restrict__ cls,
                                                     const int* __restrict__ msk,
                                                     float* __restrict__ psum,
                                                     int* __restrict__ pcnt) {
  __shared__ float ls[NC][HF];
  __shared__ int lc[NC];
  int tid = threadIdx.x;
  #pragma unroll
  for (int c = 0; c < NC; ++c) ls[c][tid] = 0.f;
  if (tid < NC) lc[tid] = 0;
  __syncthreads();
  int t0 = blockIdx.x * 256;
  for (int t = t0; t < t0 + 256; ++t) {
    int cl = cls[t];
    int mk = msk[t];
    if (mk > 0 && cl < NC) {            // uniform across block
      ls[cl][tid] += feat[(size_t)t * HF + tid];
      if (tid == 0) lc[cl]++;
    }
  }
  __syncthreads();
  for (int c = 0; c < NC; ++c) atomicAdd(&psum[c * HF + tid], ls[c][tid]);
  if (tid < NC) atomicAdd(&pcnt[tid], lc[tid]);
}

__global__ void k_proto_final(const float* __restrict__ psum,
                              const int* __restrict__ pcnt,
                              float* __restrict__ protos) {
  int c = blockIdx.x, h = threadIdx.x;
  int n = pcnt[c];
  protos[c * HF + h] = (n > 0) ? psum[c * HF + h] / (float)n : 0.f;
}

// ---------------- logits: -||qf - proto||^2 ----------------
__global__ __launch_bounds__(256) void k_logits(const float* __restrict__ feat,
                                                const float* __restrict__ protos,
                                                float* __restrict__ out) {
  int i = blockIdx.x * 256 + threadIdx.x;
  if (i >= SEQ * NC) return;
  int s = i / NC, c = i % NC;
  const float* qf = feat + (size_t)(NSUP + s) * HF;
  const float* pr = protos + c * HF;
  float acc = 0.f;
  #pragma unroll 8
  for (int h = 0; h < HF; ++h) {
    float d = qf[h] - pr[h];
    acc += d * d;
  }
  out[i] = -acc;
}

extern "C" void kernel_launch(void* const* d_in, const int* in_sizes, int n_in,
                              void* d_out, int out_size, void* d_ws, size_t ws_size,
                              hipStream_t stream) {
  const int*   sup_in  = (const int*)d_in[0];
  const int*   sup_out = (const int*)d_in[1];
  const int*   qry_in  = (const int*)d_in[2];
  const int*   sup_msk = (const int*)d_in[3];
  const float* emb     = (const float*)d_in[4];
  const float* Wqkv    = (const float*)d_in[5];
  const float* bqkv    = (const float*)d_in[6];
  const float* Wo      = (const float*)d_in[7];
  const float* bo      = (const float*)d_in[8];
  const float* ln1s    = (const float*)d_in[9];
  const float* ln1b    = (const float*)d_in[10];
  const float* W1      = (const float*)d_in[11];
  const float* b1      = (const float*)d_in[12];
  const float* W2      = (const float*)d_in[13];
  const float* b2      = (const float*)d_in[14];
  const float* ln2s    = (const float*)d_in[15];
  const float* ln2b    = (const float*)d_in[16];
  const float* Wp      = (const float*)d_in[17];
  const float* bp      = (const float*)d_in[18];

  float* ws     = (float*)d_ws;
  float* x      = ws;                              // [NTOK,128]
  float* qkv    = x + (size_t)NTOK * D;            // [NTOK,384] (also mid/feat)
  float* y      = qkv + (size_t)NTOK * 384;        // [NTOK,128]
  float* psum   = y + (size_t)NTOK * D;            // [10,256]
  int*   pcnt   = (int*)(psum + NC * HF);          // 16 ints
  float* protos = psum + NC * HF + 16;             // [10,256]
  float* outp   = (float*)d_out;

  hipMemsetAsync(psum, 0, NC * HF * sizeof(float) + 16 * sizeof(int), stream);

  k_embed<<<dim3((NTOK * D) / 256), 256, 0, stream>>>(sup_in, qry_in, emb, x);

  for (int l = 0; l < NL; ++l) {
    k_gemm<false><<<dim3(NTOK / 128, 3), 256, 0, stream>>>(
        x, D, Wqkv + (size_t)l * 384 * D, bqkv + l * 384, qkv, NTOK, 384, D);
    k_attn<<<dim3(NB * NH, 2), 256, 0, stream>>>(qkv);
    k_gemm<false><<<dim3(NTOK / 128, 1), 256, 0, stream>>>(
        qkv, 384, Wo + (size_t)l * D * D, bo + l * D, y, NTOK, D, D);
    k_add_ln<<<dim3(NTOK / 4), 256, 0, stream>>>(x, y, ln1s + l * D, ln1b + l * D);
    k_gemm<true><<<dim3(NTOK / 128, 2), 256, 0, stream>>>(
        x, D, W1 + (size_t)l * HF * D, b1 + l * HF, qkv, NTOK, HF, D);
    k_gemm<false><<<dim3(NTOK / 128, 1), 256, 0, stream>>>(
        qkv, HF, W2 + (size_t)l * D * HF, b2 + l * D, y, NTOK, D, HF);
    k_add_ln<<<dim3(NTOK / 4), 256, 0, stream>>>(x, y, ln2s + l * D, ln2b + l * D);
  }

  k_gemm<false><<<dim3(NTOK / 128, 2), 256, 0, stream>>>(
      x, D, Wp, bp, qkv, NTOK, HF, D);
  k_proto_accum<<<dim3(NSUP / 256), 256, 0, stream>>>(qkv, sup_out, sup_msk, psum, pcnt);
  k_proto_final<<<dim3(NC), 256, 0, stream>>>(psum, pcnt, protos);
  k_logits<<<dim3((SEQ * NC + 255) / 256), 256, 0, stream>>>(qkv, protos, outp);
}

// Round 4
// 2417.993 us; speedup vs baseline: 2.0120x; 2.0120x over previous
//
#include <hip/hip_runtime.h>
#include <hip/hip_bf16.h>

constexpr int D    = 128;   // d_model
constexpr int HF   = 256;   // ffn / output dim
constexpr int NH   = 4;
constexpr int DH   = 32;
constexpr int NL   = 3;
constexpr int SEQ  = 1024;
constexpr int NB   = 65;    // 64 support + 1 query
constexpr int NTOK = NB * SEQ;   // 66560
constexpr int NSUP = 64 * SEQ;   // 65536
constexpr int NC   = 10;

using u16 = unsigned short;
using u32 = unsigned int;
typedef __bf16 bf16x8 __attribute__((ext_vector_type(8)));
typedef float  f32x4  __attribute__((ext_vector_type(4)));
typedef u16    u16x4  __attribute__((ext_vector_type(4)));
typedef u16    u16x8  __attribute__((ext_vector_type(8)));

// ---------------- embedding ----------------
__global__ __launch_bounds__(256) void k_embed(const int* __restrict__ sup,
                                               const int* __restrict__ qry,
                                               const float* __restrict__ emb,
                                               float* __restrict__ x) {
  int64_t i = (int64_t)blockIdx.x * 256 + threadIdx.x;
  int tok_i = (int)(i >> 7);
  int d = (int)(i & 127);
  int t = tok_i < NSUP ? sup[tok_i] : qry[tok_i - NSUP];
  x[i] = emb[t * D + d];
}

// ---------------- GEMM: C[m,n] = sum_k A[m,k]*B[n,k] + bias[n] ----------------
template<bool RELU, bool BF16OUT>
__global__ __launch_bounds__(256) void k_gemm(const float* __restrict__ A, int lda,
                                              const float* __restrict__ B,
                                              const float* __restrict__ bias,
                                              void* __restrict__ Cm,
                                              int M, int N, int K) {
  constexpr int BK = 32;
  __shared__ float As[BK][132];
  __shared__ float Bs[BK][132];
  const int m0 = blockIdx.x * 128;
  const int n0 = blockIdx.y * 128;
  const int tid = threadIdx.x;
  const int tm = tid & 15;
  const int tn = tid >> 4;
  float acc[8][8] = {};

  for (int k0 = 0; k0 < K; k0 += BK) {
    __syncthreads();
    #pragma unroll
    for (int it = 0; it < 4; ++it) {
      int idx = tid + it * 256;
      int r = idx >> 3;
      int c4 = (idx & 7) * 4;
      float4 va = *(const float4*)(A + (size_t)(m0 + r) * lda + k0 + c4);
      As[c4 + 0][r] = va.x; As[c4 + 1][r] = va.y;
      As[c4 + 2][r] = va.z; As[c4 + 3][r] = va.w;
      float4 vb = *(const float4*)(B + (size_t)(n0 + r) * K + k0 + c4);
      Bs[c4 + 0][r] = vb.x; Bs[c4 + 1][r] = vb.y;
      Bs[c4 + 2][r] = vb.z; Bs[c4 + 3][r] = vb.w;
    }
    __syncthreads();
    #pragma unroll 4
    for (int k = 0; k < BK; ++k) {
      float4 a0 = *(const float4*)&As[k][tm * 4];
      float4 a1 = *(const float4*)&As[k][64 + tm * 4];
      float4 b0 = *(const float4*)&Bs[k][tn * 4];
      float4 b1 = *(const float4*)&Bs[k][64 + tn * 4];
      float a_[8] = {a0.x, a0.y, a0.z, a0.w, a1.x, a1.y, a1.z, a1.w};
      float b_[8] = {b0.x, b0.y, b0.z, b0.w, b1.x, b1.y, b1.z, b1.w};
      #pragma unroll
      for (int i = 0; i < 8; ++i)
        #pragma unroll
        for (int j = 0; j < 8; ++j)
          acc[i][j] += a_[i] * b_[j];
    }
  }

  #pragma unroll
  for (int i = 0; i < 8; ++i) {
    int m = m0 + ((i < 4) ? (tm * 4 + i) : (64 + tm * 4 + i - 4));
    #pragma unroll
    for (int half = 0; half < 2; ++half) {
      int nb = half * 64 + tn * 4;
      float o[4];
      #pragma unroll
      for (int j = 0; j < 4; ++j) {
        o[j] = acc[i][half * 4 + j] + bias[n0 + nb + j];
        if (RELU) o[j] = fmaxf(o[j], 0.f);
      }
      if (BF16OUT) {
        u16* crow = (u16*)Cm + (size_t)m * N + n0;
        u16x4 pk;
        #pragma unroll
        for (int j = 0; j < 4; ++j)
          pk[j] = __builtin_bit_cast(u16, (__bf16)o[j]);
        *(u16x4*)(crow + nb) = pk;
      } else {
        float* crow = (float*)Cm + (size_t)m * N + n0;
        float4 of = {o[0], o[1], o[2], o[3]};
        *(float4*)(crow + nb) = of;
      }
    }
  }
}

// ---------------- MFMA flash attention, wave-autonomous ----------------
// qkvb: bf16 [NTOK][384] = [q|k|v]; out: fp32 [NTOK][128].
// grid (NB*NH, 64); block 64 = ONE wave; wave owns 16 q rows. No __syncthreads.
// mfma_f32_16x16x32_bf16 C/D: col=lane&15, row=(lane>>4)*4+reg.
__global__ __launch_bounds__(64) void k_attn_mfma(const u16* __restrict__ qkvb,
                                                  float* __restrict__ out) {
  const int bh = blockIdx.x;
  const int b = bh >> 2, h = bh & 3;
  const int l = threadIdx.x;      // 0..63
  const int g = l >> 4;           // lane group 0..3
  const int c16 = l & 15;         // 0..15
  const int qbase = blockIdx.y * 16;

  __shared__ u16 Vt[32 * 72];     // V^T tile: [dh][kp], row stride 72 (36 u32)
  __shared__ u16 Plds[64 * 18];   // P: [kp][q], row stride 18

  const size_t tok0 = (size_t)b * SEQ;
  constexpr float KSL = 0.25500446f;   // 1/sqrt(32) * log2(e)

  // A-fragment: lane holds Q[qbase + c16][g*8 + j]
  bf16x8 qf = *(const bf16x8*)(qkvb + (tok0 + qbase + c16) * 384 + h * 32 + g * 8);

  f32x4 of0 = {0.f, 0.f, 0.f, 0.f}, of1 = {0.f, 0.f, 0.f, 0.f};
  float m[4], lsum[4];
  #pragma unroll
  for (int r = 0; r < 4; ++r) { m[r] = -1e30f; lsum[r] = 0.f; }

  // V staging: lane -> (kp pair = l&31, dh half = l>>5). 64 lanes cover 64 kp x 32 dh.
  const int pair = l & 31;
  const int half = l >> 5;
  const u16* vsrc   = qkvb + tok0 * 384 + 256 + h * 32 + half * 16;
  const u16* kbase0 = qkvb + tok0 * 384 + 128 + h * 32 + g * 8 + (size_t)c16 * 384;
  u32* Vtw = (u32*)Vt;
  u32* pw  = (u32*)Plds;
  const f32x4 zf = {0.f, 0.f, 0.f, 0.f};

  for (int kt = 0; kt < SEQ; kt += 64) {
    // global loads: 2 V rows x 16 dh each (32B = two u16x8), 4 K fragments
    const u16* vr0 = vsrc + (size_t)(kt + pair * 2) * 384;
    const u16* vr1 = vsrc + (size_t)(kt + pair * 2 + 1) * 384;
    u16x8 va_lo = *(const u16x8*)(vr0);
    u16x8 va_hi = *(const u16x8*)(vr0 + 8);
    u16x8 vb_lo = *(const u16x8*)(vr1);
    u16x8 vb_hi = *(const u16x8*)(vr1 + 8);
    const u16* kb = kbase0 + (size_t)kt * 384;
    bf16x8 kf0 = *(const bf16x8*)(kb);
    bf16x8 kf1 = *(const bf16x8*)(kb + 16 * 384);
    bf16x8 kf2 = *(const bf16x8*)(kb + 32 * 384);
    bf16x8 kf3 = *(const bf16x8*)(kb + 48 * 384);

    // stage V^T (packed kp pairs): Vt[dh][kp]
    #pragma unroll
    for (int j = 0; j < 8; ++j) {
      Vtw[(half * 16 + j) * 36 + pair]     = (u32)va_lo[j] | ((u32)vb_lo[j] << 16);
      Vtw[(half * 16 + 8 + j) * 36 + pair] = (u32)va_hi[j] | ((u32)vb_hi[j] << 16);
    }
    __threadfence_block();
    __builtin_amdgcn_sched_barrier(0);

    // S tiles: lane holds S[q = qbase+4g+r][key = kt + 16t + c16] in s_t[r]
    f32x4 s0 = __builtin_amdgcn_mfma_f32_16x16x32_bf16(qf, kf0, zf, 0, 0, 0);
    f32x4 s1 = __builtin_amdgcn_mfma_f32_16x16x32_bf16(qf, kf1, zf, 0, 0, 0);
    f32x4 s2 = __builtin_amdgcn_mfma_f32_16x16x32_bf16(qf, kf2, zf, 0, 0, 0);
    f32x4 s3 = __builtin_amdgcn_mfma_f32_16x16x32_bf16(qf, kf3, zf, 0, 0, 0);

    float ss[4][4];
    #pragma unroll
    for (int r = 0; r < 4; ++r) {
      ss[0][r] = s0[r] * KSL; ss[1][r] = s1[r] * KSL;
      ss[2][r] = s2[r] * KSL; ss[3][r] = s3[r] * KSL;
    }

    // online softmax per q-row (reduce over the 16 lanes of the row group)
    #pragma unroll
    for (int r = 0; r < 4; ++r) {
      float tm = fmaxf(fmaxf(ss[0][r], ss[1][r]), fmaxf(ss[2][r], ss[3][r]));
      tm = fmaxf(tm, __shfl_xor(tm, 1));
      tm = fmaxf(tm, __shfl_xor(tm, 2));
      tm = fmaxf(tm, __shfl_xor(tm, 4));
      tm = fmaxf(tm, __shfl_xor(tm, 8));
      float mnew = fmaxf(m[r], tm);
      float c0 = exp2f(m[r] - mnew);
      float ps = 0.f;
      #pragma unroll
      for (int t = 0; t < 4; ++t) { ss[t][r] = exp2f(ss[t][r] - mnew); ps += ss[t][r]; }
      ps += __shfl_xor(ps, 1);
      ps += __shfl_xor(ps, 2);
      ps += __shfl_xor(ps, 4);
      ps += __shfl_xor(ps, 8);
      lsum[r] = lsum[r] * c0 + ps;
      m[r] = mnew;
      of0[r] *= c0; of1[r] *= c0;
    }

    // P -> LDS, layout [kp][q], packed q-pairs
    #pragma unroll
    for (int t = 0; t < 4; ++t)
      #pragma unroll
      for (int rr = 0; rr < 4; rr += 2) {
        u32 w = (u32)__builtin_bit_cast(u16, (__bf16)ss[t][rr])
              | ((u32)__builtin_bit_cast(u16, (__bf16)ss[t][rr + 1]) << 16);
        pw[((16 * t + c16) * 18 + g * 4 + rr) >> 1] = w;
      }
    __threadfence_block();
    __builtin_amdgcn_sched_barrier(0);

    // PV: O[q][dh] += sum_kk P[q][kk] V[kt+kk][dh], two kk-chunks of 32
    #pragma unroll
    for (int cc = 0; cc < 2; ++cc) {
      union { u16 u[8]; bf16x8 v; } pa;
      #pragma unroll
      for (int j = 0; j < 8; ++j)
        pa.u[j] = Plds[(cc * 32 + g * 8 + j) * 18 + c16];
      bf16x8 v0 = *(const bf16x8*)(Vt + (size_t)c16 * 72 + cc * 32 + g * 8);
      bf16x8 v1 = *(const bf16x8*)(Vt + (size_t)(16 + c16) * 72 + cc * 32 + g * 8);
      of0 = __builtin_amdgcn_mfma_f32_16x16x32_bf16(pa.v, v0, of0, 0, 0, 0);
      of1 = __builtin_amdgcn_mfma_f32_16x16x32_bf16(pa.v, v1, of1, 0, 0, 0);
    }
    __threadfence_block();
    __builtin_amdgcn_sched_barrier(0);
  }

  #pragma unroll
  for (int r = 0; r < 4; ++r) {
    float inv = 1.f / lsum[r];
    size_t row = tok0 + qbase + g * 4 + r;
    out[row * 128 + h * 32 + c16]      = of0[r] * inv;
    out[row * 128 + h * 32 + 16 + c16] = of1[r] * inv;
  }
}

// ---------------- residual add + LayerNorm (in place on x) ----------------
__global__ __launch_bounds__(256) void k_add_ln(float* __restrict__ x,
                                                const float* __restrict__ y,
                                                const float* __restrict__ gamma,
                                                const float* __restrict__ beta) {
  int row = blockIdx.x * 4 + (threadIdx.x >> 6);
  int lane = threadIdx.x & 63;
  float* xr = x + (size_t)row * D;
  const float* yr = y + (size_t)row * D;
  float2 v = *(float2*)(xr + lane * 2);
  float2 w = *(const float2*)(yr + lane * 2);
  float a = v.x + w.x, b = v.y + w.y;
  float sum = a + b;
  #pragma unroll
  for (int off = 32; off; off >>= 1) sum += __shfl_xor(sum, off);
  float mean = sum * (1.f / 128.f);
  float da = a - mean, db = b - mean;
  float vs = da * da + db * db;
  #pragma unroll
  for (int off = 32; off; off >>= 1) vs += __shfl_xor(vs, off);
  float inv = 1.f / sqrtf(vs * (1.f / 128.f) + 1e-5f);
  float2 o;
  o.x = da * inv * gamma[lane * 2 + 0] + beta[lane * 2 + 0];
  o.y = db * inv * gamma[lane * 2 + 1] + beta[lane * 2 + 1];
  *(float2*)(xr + lane * 2) = o;
}

// ---------------- prototype accumulation ----------------
__global__ __launch_bounds__(256) void k_proto_accum(const float* __restrict__ feat,
                                                     const int* __restrict__ cls,
                                                     const int* __restrict__ msk,
                                                     float* __restrict__ psum,
                                                     int* __restrict__ pcnt) {
  __shared__ float ls[NC][HF];
  __shared__ int lc[NC];
  int tid = threadIdx.x;
  #pragma unroll
  for (int c = 0; c < NC; ++c) ls[c][tid] = 0.f;
  if (tid < NC) lc[tid] = 0;
  __syncthreads();
  int t0 = blockIdx.x * 256;
  for (int t = t0; t < t0 + 256; ++t) {
    int cl = cls[t];
    int mk = msk[t];
    if (mk > 0 && cl < NC) {
      ls[cl][tid] += feat[(size_t)t * HF + tid];
      if (tid == 0) lc[cl]++;
    }
  }
  __syncthreads();
  for (int c = 0; c < NC; ++c) atomicAdd(&psum[c * HF + tid], ls[c][tid]);
  if (tid < NC) atomicAdd(&pcnt[tid], lc[tid]);
}

__global__ void k_proto_final(const float* __restrict__ psum,
                              const int* __restrict__ pcnt,
                              float* __restrict__ protos) {
  int c = blockIdx.x, h = threadIdx.x;
  int n = pcnt[c];
  protos[c * HF + h] = (n > 0) ? psum[c * HF + h] / (float)n : 0.f;
}

// ---------------- logits ----------------
__global__ __launch_bounds__(256) void k_logits(const float* __restrict__ feat,
                                                const float* __restrict__ protos,
                                                float* __restrict__ out) {
  int i = blockIdx.x * 256 + threadIdx.x;
  if (i >= SEQ * NC) return;
  int s = i / NC, c = i % NC;
  const float* qf = feat + (size_t)(NSUP + s) * HF;
  const float* pr = protos + c * HF;
  float acc = 0.f;
  #pragma unroll 8
  for (int h = 0; h < HF; ++h) {
    float d = qf[h] - pr[h];
    acc += d * d;
  }
  out[i] = -acc;
}

extern "C" void kernel_launch(void* const* d_in, const int* in_sizes, int n_in,
                              void* d_out, int out_size, void* d_ws, size_t ws_size,
                              hipStream_t stream) {
  const int*   sup_in  = (const int*)d_in[0];
  const int*   sup_out = (const int*)d_in[1];
  const int*   qry_in  = (const int*)d_in[2];
  const int*   sup_msk = (const int*)d_in[3];
  const float* emb     = (const float*)d_in[4];
  const float* Wqkv    = (const float*)d_in[5];
  const float* bqkv    = (const float*)d_in[6];
  const float* Wo      = (const float*)d_in[7];
  const float* bo      = (const float*)d_in[8];
  const float* ln1s    = (const float*)d_in[9];
  const float* ln1b    = (const float*)d_in[10];
  const float* W1      = (const float*)d_in[11];
  const float* b1      = (const float*)d_in[12];
  const float* W2      = (const float*)d_in[13];
  const float* b2      = (const float*)d_in[14];
  const float* ln2s    = (const float*)d_in[15];
  const float* ln2b    = (const float*)d_in[16];
  const float* Wp      = (const float*)d_in[17];
  const float* bp      = (const float*)d_in[18];

  // Buffers (all out-of-place dataflow):
  //   x [NTOK,128] f32 | y [NTOK,256] f32 | Uf: qkvb bf16 [NTOK,384] OR f32 [NTOK,128] temp
  float* ws = (float*)d_ws;
  float* x  = ws;                               // NTOK*128 f32
  float* y  = x + (size_t)NTOK * D;             // NTOK*256 f32
  float* Uf = y + (size_t)NTOK * HF;            // NTOK*192 f32 region
  u16*   qkvb = (u16*)Uf;                       // NTOK*384 bf16 (same bytes)
  float* psum = Uf + (size_t)NTOK * 192;        // [10,256]
  int*   pcnt = (int*)(psum + NC * HF);         // 16 ints
  float* protos = psum + NC * HF + 16;          // [10,256]
  float* outp = (float*)d_out;

  hipMemsetAsync(psum, 0, NC * HF * sizeof(float) + 16 * sizeof(int), stream);

  k_embed<<<dim3((NTOK * D) / 256), 256, 0, stream>>>(sup_in, qry_in, emb, x);

  for (int l = 0; l < NL; ++l) {
    // QKV (bf16 out): x -> qkvb
    k_gemm<false, true><<<dim3(NTOK / 128, 3), 256, 0, stream>>>(
        x, D, Wqkv + (size_t)l * 384 * D, bqkv + l * 384, qkvb, NTOK, 384, D);
    // attention: qkvb -> y (stride 128)
    k_attn_mfma<<<dim3(NB * NH, 64), 64, 0, stream>>>(qkvb, y);
    // Wo: y -> Uf (out-of-place; qkvb dead now)
    k_gemm<false, false><<<dim3(NTOK / 128, 1), 256, 0, stream>>>(
        y, D, Wo + (size_t)l * D * D, bo + l * D, Uf, NTOK, D, D);
    k_add_ln<<<dim3(NTOK / 4), 256, 0, stream>>>(x, Uf, ln1s + l * D, ln1b + l * D);
    // FFN: W1: x -> y [NTOK,256];  W2: y -> Uf
    k_gemm<true, false><<<dim3(NTOK / 128, 2), 256, 0, stream>>>(
        x, D, W1 + (size_t)l * HF * D, b1 + l * HF, y, NTOK, HF, D);
    k_gemm<false, false><<<dim3(NTOK / 128, 1), 256, 0, stream>>>(
        y, HF, W2 + (size_t)l * D * HF, b2 + l * D, Uf, NTOK, D, HF);
    k_add_ln<<<dim3(NTOK / 4), 256, 0, stream>>>(x, Uf, ln2s + l * D, ln2b + l * D);
  }

  // final projection: x -> y [NTOK,256]
  k_gemm<false, false><<<dim3(NTOK / 128, 2), 256, 0, stream>>>(
      x, D, Wp, bp, y, NTOK, HF, D);
  k_proto_accum<<<dim3(NSUP / 256), 256, 0, stream>>>(y, sup_out, sup_msk, psum, pcnt);
  k_proto_final<<<dim3(NC), 256, 0, stream>>>(psum, pcnt, protos);
  k_logits<<<dim3((SEQ * NC + 255) / 256), 256, 0, stream>>>(y, protos, outp);
}

// Round 5
// 1368.875 us; speedup vs baseline: 3.5541x; 1.7664x over previous
//
#include <hip/hip_runtime.h>
#include <hip/hip_bf16.h>

constexpr int D    = 128;   // d_model
constexpr int HF   = 256;   // ffn / output dim
constexpr int NH   = 4;
constexpr int DH   = 32;
constexpr int NL   = 3;
constexpr int SEQ  = 1024;
constexpr int NB   = 65;    // 64 support + 1 query
constexpr int NTOK = NB * SEQ;   // 66560
constexpr int NSUP = 64 * SEQ;   // 65536
constexpr int NC   = 10;

using u16 = unsigned short;
using u32 = unsigned int;
typedef __bf16 bf16x8 __attribute__((ext_vector_type(8)));
typedef float  f32x4  __attribute__((ext_vector_type(4)));
typedef u16    u16x8  __attribute__((ext_vector_type(8)));

static __device__ __forceinline__ u16 f2b(float f) {
  return __builtin_bit_cast(u16, (__bf16)f);
}
static __device__ __forceinline__ float b2f(u16 u) {
  return (float)__builtin_bit_cast(__bf16, u);
}

// ---------------- weight f32 -> bf16 ----------------
__global__ __launch_bounds__(256) void k_f2b(const float* __restrict__ in,
                                             u16* __restrict__ out, int n) {
  int i = blockIdx.x * 256 + threadIdx.x;
  if (i < n) out[i] = f2b(in[i]);
}

// ---------------- embedding (f32 x + bf16 xb) ----------------
__global__ __launch_bounds__(256) void k_embed(const int* __restrict__ sup,
                                               const int* __restrict__ qry,
                                               const float* __restrict__ emb,
                                               float* __restrict__ x,
                                               u16* __restrict__ xb) {
  int64_t i = (int64_t)blockIdx.x * 256 + threadIdx.x;
  int tok_i = (int)(i >> 7);
  int d = (int)(i & 127);
  int t = tok_i < NSUP ? sup[tok_i] : qry[tok_i - NSUP];
  float v = emb[t * D + d];
  x[i] = v;
  xb[i] = f2b(v);
}

// ---------------- MFMA GEMM: C[m,n] = sum_k A[m,k]*B[n,k] + bias[n] ----------------
// A: bf16 [M][K]; B: bf16 [N][K] (weight); C: f32 or bf16 [M][N].
// grid (M/128, N/128); block 256 = 4 waves; wave w owns rows m0+w*32..+32, cols n0..n0+128.
// Fragment pattern (HW-verified by attention kernel): operand lane layout
// [row=c16][k=g*8+j]; D row = g*4+r (A-side), D col = c16 (B-side).
template<bool RELU, bool BF16OUT>
__global__ __launch_bounds__(256) void k_gemm_mfma(const u16* __restrict__ A,
                                                   const u16* __restrict__ B,
                                                   const float* __restrict__ bias,
                                                   void* __restrict__ Cm,
                                                   int M, int N, int K) {
  const int tid = threadIdx.x;
  const int w = tid >> 6, l = tid & 63;
  const int g = l >> 4, c16 = l & 15;
  const int m0 = blockIdx.x * 128 + w * 32;
  const int n0 = blockIdx.y * 128;

  f32x4 acc[2][8] = {};
  const u16* a0p = A + (size_t)(m0 + c16) * K + g * 8;
  const u16* a1p = a0p + (size_t)16 * K;
  const u16* bp  = B + (size_t)(n0 + c16) * K + g * 8;

  for (int k = 0; k < K; k += 32) {
    bf16x8 a0 = *(const bf16x8*)(a0p + k);
    bf16x8 a1 = *(const bf16x8*)(a1p + k);
    #pragma unroll
    for (int nc = 0; nc < 8; ++nc) {
      bf16x8 b = *(const bf16x8*)(bp + (size_t)(nc * 16) * K + k);
      acc[0][nc] = __builtin_amdgcn_mfma_f32_16x16x32_bf16(a0, b, acc[0][nc], 0, 0, 0);
      acc[1][nc] = __builtin_amdgcn_mfma_f32_16x16x32_bf16(a1, b, acc[1][nc], 0, 0, 0);
    }
  }

  #pragma unroll
  for (int nc = 0; nc < 8; ++nc) {
    const int n_ = n0 + nc * 16 + c16;
    const float bs = bias[n_];
    #pragma unroll
    for (int mf = 0; mf < 2; ++mf)
      #pragma unroll
      for (int r = 0; r < 4; ++r) {
        const int m_ = m0 + mf * 16 + g * 4 + r;
        float v = acc[mf][nc][r] + bs;
        if (RELU) v = fmaxf(v, 0.f);
        if (BF16OUT) ((u16*)Cm)[(size_t)m_ * N + n_] = f2b(v);
        else         ((float*)Cm)[(size_t)m_ * N + n_] = v;
      }
  }
}

// ---------------- MFMA flash attention, wave-autonomous ----------------
// qkvb: bf16 [NTOK][384] = [q|k|v]; out: bf16 [NTOK][128].
// grid (qblock=64, bh=260): consecutive blocks share (b,h) K/V -> L2-resident.
__global__ __launch_bounds__(64) void k_attn_mfma(const u16* __restrict__ qkvb,
                                                  u16* __restrict__ out) {
  const int bh = blockIdx.y;
  const int b = bh >> 2, h = bh & 3;
  const int l = threadIdx.x;      // 0..63
  const int g = l >> 4;           // lane group 0..3
  const int c16 = l & 15;         // 0..15
  const int qbase = blockIdx.x * 16;

  __shared__ u16 Vt[32 * 72];     // V^T tile: [dh][kp], row stride 72 (36 u32)
  __shared__ u16 Plds[64 * 18];   // P: [kp][q], row stride 18

  const size_t tok0 = (size_t)b * SEQ;
  constexpr float KSL = 0.25500446f;   // 1/sqrt(32) * log2(e)

  bf16x8 qf = *(const bf16x8*)(qkvb + (tok0 + qbase + c16) * 384 + h * 32 + g * 8);

  f32x4 of0 = {0.f, 0.f, 0.f, 0.f}, of1 = {0.f, 0.f, 0.f, 0.f};
  float m[4], lsum[4];
  #pragma unroll
  for (int r = 0; r < 4; ++r) { m[r] = -1e30f; lsum[r] = 0.f; }

  const int pair = l & 31;
  const int half = l >> 5;
  const u16* vsrc   = qkvb + tok0 * 384 + 256 + h * 32 + half * 16;
  const u16* kbase0 = qkvb + tok0 * 384 + 128 + h * 32 + g * 8 + (size_t)c16 * 384;
  u32* Vtw = (u32*)Vt;
  u32* pw  = (u32*)Plds;
  const f32x4 zf = {0.f, 0.f, 0.f, 0.f};

  for (int kt = 0; kt < SEQ; kt += 64) {
    const u16* vr0 = vsrc + (size_t)(kt + pair * 2) * 384;
    const u16* vr1 = vsrc + (size_t)(kt + pair * 2 + 1) * 384;
    u16x8 va_lo = *(const u16x8*)(vr0);
    u16x8 va_hi = *(const u16x8*)(vr0 + 8);
    u16x8 vb_lo = *(const u16x8*)(vr1);
    u16x8 vb_hi = *(const u16x8*)(vr1 + 8);
    const u16* kb = kbase0 + (size_t)kt * 384;
    bf16x8 kf0 = *(const bf16x8*)(kb);
    bf16x8 kf1 = *(const bf16x8*)(kb + 16 * 384);
    bf16x8 kf2 = *(const bf16x8*)(kb + 32 * 384);
    bf16x8 kf3 = *(const bf16x8*)(kb + 48 * 384);

    #pragma unroll
    for (int j = 0; j < 8; ++j) {
      Vtw[(half * 16 + j) * 36 + pair]     = (u32)va_lo[j] | ((u32)vb_lo[j] << 16);
      Vtw[(half * 16 + 8 + j) * 36 + pair] = (u32)va_hi[j] | ((u32)vb_hi[j] << 16);
    }
    __threadfence_block();
    __builtin_amdgcn_sched_barrier(0);

    f32x4 s0 = __builtin_amdgcn_mfma_f32_16x16x32_bf16(qf, kf0, zf, 0, 0, 0);
    f32x4 s1 = __builtin_amdgcn_mfma_f32_16x16x32_bf16(qf, kf1, zf, 0, 0, 0);
    f32x4 s2 = __builtin_amdgcn_mfma_f32_16x16x32_bf16(qf, kf2, zf, 0, 0, 0);
    f32x4 s3 = __builtin_amdgcn_mfma_f32_16x16x32_bf16(qf, kf3, zf, 0, 0, 0);

    float ss[4][4];
    #pragma unroll
    for (int r = 0; r < 4; ++r) {
      ss[0][r] = s0[r] * KSL; ss[1][r] = s1[r] * KSL;
      ss[2][r] = s2[r] * KSL; ss[3][r] = s3[r] * KSL;
    }

    #pragma unroll
    for (int r = 0; r < 4; ++r) {
      float tm = fmaxf(fmaxf(ss[0][r], ss[1][r]), fmaxf(ss[2][r], ss[3][r]));
      tm = fmaxf(tm, __shfl_xor(tm, 1));
      tm = fmaxf(tm, __shfl_xor(tm, 2));
      tm = fmaxf(tm, __shfl_xor(tm, 4));
      tm = fmaxf(tm, __shfl_xor(tm, 8));
      float mnew = fmaxf(m[r], tm);
      float c0 = exp2f(m[r] - mnew);
      float ps = 0.f;
      #pragma unroll
      for (int t = 0; t < 4; ++t) { ss[t][r] = exp2f(ss[t][r] - mnew); ps += ss[t][r]; }
      ps += __shfl_xor(ps, 1);
      ps += __shfl_xor(ps, 2);
      ps += __shfl_xor(ps, 4);
      ps += __shfl_xor(ps, 8);
      lsum[r] = lsum[r] * c0 + ps;
      m[r] = mnew;
      of0[r] *= c0; of1[r] *= c0;
    }

    #pragma unroll
    for (int t = 0; t < 4; ++t)
      #pragma unroll
      for (int rr = 0; rr < 4; rr += 2) {
        u32 wv = (u32)f2b(ss[t][rr]) | ((u32)f2b(ss[t][rr + 1]) << 16);
        pw[((16 * t + c16) * 18 + g * 4 + rr) >> 1] = wv;
      }
    __threadfence_block();
    __builtin_amdgcn_sched_barrier(0);

    #pragma unroll
    for (int cc = 0; cc < 2; ++cc) {
      union { u16 u[8]; bf16x8 v; } pa;
      #pragma unroll
      for (int j = 0; j < 8; ++j)
        pa.u[j] = Plds[(cc * 32 + g * 8 + j) * 18 + c16];
      bf16x8 v0 = *(const bf16x8*)(Vt + (size_t)c16 * 72 + cc * 32 + g * 8);
      bf16x8 v1 = *(const bf16x8*)(Vt + (size_t)(16 + c16) * 72 + cc * 32 + g * 8);
      of0 = __builtin_amdgcn_mfma_f32_16x16x32_bf16(pa.v, v0, of0, 0, 0, 0);
      of1 = __builtin_amdgcn_mfma_f32_16x16x32_bf16(pa.v, v1, of1, 0, 0, 0);
    }
    __threadfence_block();
    __builtin_amdgcn_sched_barrier(0);
  }

  #pragma unroll
  for (int r = 0; r < 4; ++r) {
    float inv = 1.f / lsum[r];
    size_t row = tok0 + qbase + g * 4 + r;
    out[row * 128 + h * 32 + c16]      = f2b(of0[r] * inv);
    out[row * 128 + h * 32 + 16 + c16] = f2b(of1[r] * inv);
  }
}

// ---------------- residual add + LayerNorm (x f32 in/out, xb bf16 out) ----------------
__global__ __launch_bounds__(256) void k_add_ln(float* __restrict__ x,
                                                u16* __restrict__ xb,
                                                const float* __restrict__ y,
                                                const float* __restrict__ gamma,
                                                const float* __restrict__ beta) {
  int row = blockIdx.x * 4 + (threadIdx.x >> 6);
  int lane = threadIdx.x & 63;
  float* xr = x + (size_t)row * D;
  const float* yr = y + (size_t)row * D;
  float2 v = *(float2*)(xr + lane * 2);
  float2 w = *(const float2*)(yr + lane * 2);
  float a = v.x + w.x, b = v.y + w.y;
  float sum = a + b;
  #pragma unroll
  for (int off = 32; off; off >>= 1) sum += __shfl_xor(sum, off);
  float mean = sum * (1.f / 128.f);
  float da = a - mean, db = b - mean;
  float vs = da * da + db * db;
  #pragma unroll
  for (int off = 32; off; off >>= 1) vs += __shfl_xor(vs, off);
  float inv = 1.f / sqrtf(vs * (1.f / 128.f) + 1e-5f);
  float2 o;
  o.x = da * inv * gamma[lane * 2 + 0] + beta[lane * 2 + 0];
  o.y = db * inv * gamma[lane * 2 + 1] + beta[lane * 2 + 1];
  *(float2*)(xr + lane * 2) = o;
  u32 pk = (u32)f2b(o.x) | ((u32)f2b(o.y) << 16);
  *(u32*)(xb + (size_t)row * D + lane * 2) = pk;
}

// ---------------- prototype accumulation (bf16 feat) ----------------
__global__ __launch_bounds__(256) void k_proto_accum(const u16* __restrict__ feat,
                                                     const int* __restrict__ cls,
                                                     const int* __restrict__ msk,
                                                     float* __restrict__ psum,
                                                     int* __restrict__ pcnt) {
  __shared__ float ls[NC][HF];
  __shared__ int lc[NC];
  int tid = threadIdx.x;
  #pragma unroll
  for (int c = 0; c < NC; ++c) ls[c][tid] = 0.f;
  if (tid < NC) lc[tid] = 0;
  __syncthreads();
  int t0 = blockIdx.x * 256;
  for (int t = t0; t < t0 + 256; ++t) {
    int cl = cls[t];
    int mk = msk[t];
    if (mk > 0 && cl < NC) {
      ls[cl][tid] += b2f(feat[(size_t)t * HF + tid]);
      if (tid == 0) lc[cl]++;
    }
  }
  __syncthreads();
  for (int c = 0; c < NC; ++c) atomicAdd(&psum[c * HF + tid], ls[c][tid]);
  if (tid < NC) atomicAdd(&pcnt[tid], lc[tid]);
}

__global__ void k_proto_final(const float* __restrict__ psum,
                              const int* __restrict__ pcnt,
                              float* __restrict__ protos) {
  int c = blockIdx.x, h = threadIdx.x;
  int n = pcnt[c];
  protos[c * HF + h] = (n > 0) ? psum[c * HF + h] / (float)n : 0.f;
}

// ---------------- logits ----------------
__global__ __launch_bounds__(256) void k_logits(const u16* __restrict__ feat,
                                                const float* __restrict__ protos,
                                                float* __restrict__ out) {
  int i = blockIdx.x * 256 + threadIdx.x;
  if (i >= SEQ * NC) return;
  int s = i / NC, c = i % NC;
  const u16* qf = feat + (size_t)(NSUP + s) * HF;
  const float* pr = protos + c * HF;
  float acc = 0.f;
  #pragma unroll 8
  for (int h = 0; h < HF; ++h) {
    float d = b2f(qf[h]) - pr[h];
    acc += d * d;
  }
  out[i] = -acc;
}

extern "C" void kernel_launch(void* const* d_in, const int* in_sizes, int n_in,
                              void* d_out, int out_size, void* d_ws, size_t ws_size,
                              hipStream_t stream) {
  const int*   sup_in  = (const int*)d_in[0];
  const int*   sup_out = (const int*)d_in[1];
  const int*   qry_in  = (const int*)d_in[2];
  const int*   sup_msk = (const int*)d_in[3];
  const float* emb     = (const float*)d_in[4];
  const float* Wqkv    = (const float*)d_in[5];
  const float* bqkv    = (const float*)d_in[6];
  const float* Wo      = (const float*)d_in[7];
  const float* bo      = (const float*)d_in[8];
  const float* ln1s    = (const float*)d_in[9];
  const float* ln1b    = (const float*)d_in[10];
  const float* W1      = (const float*)d_in[11];
  const float* b1      = (const float*)d_in[12];
  const float* W2      = (const float*)d_in[13];
  const float* b2      = (const float*)d_in[14];
  const float* ln2s    = (const float*)d_in[15];
  const float* ln2b    = (const float*)d_in[16];
  const float* Wp      = (const float*)d_in[17];
  const float* bp      = (const float*)d_in[18];

  // ws layout (f32 units): x[NTOK*128] | y[NTOK*128] | xb bf16[NTOK*128] |
  //   yb bf16[NTOK*128] | U bf16[NTOK*384] (qkvb; midb/featb alias) |
  //   weights bf16 | psum | pcnt | protos
  float* ws = (float*)d_ws;
  float* x  = ws;
  float* y  = x + (size_t)NTOK * D;
  u16*   xb = (u16*)(y + (size_t)NTOK * D);
  u16*   yb = xb + (size_t)NTOK * D;
  u16*   U  = yb + (size_t)NTOK * D;            // NTOK*384 u16
  u16*   qkvb = U;
  u16*   midb = U;                               // [NTOK,256] (qkvb dead when written)
  u16*   featb = U;                              // [NTOK,256] (after last layer)
  u16*   wqkvb = U + (size_t)NTOK * 384;         // 147456
  u16*   wob   = wqkvb + 3 * 384 * 128;          // 49152
  u16*   w1b   = wob + 3 * 128 * 128;            // 98304
  u16*   w2b   = w1b + 3 * 256 * 128;            // 98304
  u16*   wpb   = w2b + 3 * 128 * 256;            // 32768
  float* psum  = (float*)(((size_t)(wpb + 256 * 128) + 15) & ~(size_t)15);
  int*   pcnt  = (int*)(psum + NC * HF);
  float* protos = psum + NC * HF + 16;
  float* outp = (float*)d_out;

  hipMemsetAsync(psum, 0, NC * HF * sizeof(float) + 16 * sizeof(int), stream);

  // weight conversions
  k_f2b<<<dim3((3*384*128 + 255)/256), 256, 0, stream>>>(Wqkv, wqkvb, 3*384*128);
  k_f2b<<<dim3((3*128*128 + 255)/256), 256, 0, stream>>>(Wo,   wob,   3*128*128);
  k_f2b<<<dim3((3*256*128 + 255)/256), 256, 0, stream>>>(W1,   w1b,   3*256*128);
  k_f2b<<<dim3((3*128*256 + 255)/256), 256, 0, stream>>>(W2,   w2b,   3*128*256);
  k_f2b<<<dim3((256*128   + 255)/256), 256, 0, stream>>>(Wp,   wpb,   256*128);

  k_embed<<<dim3((NTOK * D) / 256), 256, 0, stream>>>(sup_in, qry_in, emb, x, xb);

  for (int l = 0; l < NL; ++l) {
    // QKV: xb -> qkvb (bf16)
    k_gemm_mfma<false, true><<<dim3(NTOK / 128, 3), 256, 0, stream>>>(
        xb, wqkvb + (size_t)l * 384 * 128, bqkv + l * 384, qkvb, NTOK, 384, D);
    // attention: qkvb -> yb (bf16)
    k_attn_mfma<<<dim3(64, NB * NH), 64, 0, stream>>>(qkvb, yb);
    // Wo: yb -> y (f32)
    k_gemm_mfma<false, false><<<dim3(NTOK / 128, 1), 256, 0, stream>>>(
        yb, wob + (size_t)l * 128 * 128, bo + l * D, y, NTOK, D, D);
    k_add_ln<<<dim3(NTOK / 4), 256, 0, stream>>>(x, xb, y, ln1s + l * D, ln1b + l * D);
    // W1 (+relu): xb -> midb (bf16)
    k_gemm_mfma<true, true><<<dim3(NTOK / 128, 2), 256, 0, stream>>>(
        xb, w1b + (size_t)l * 256 * 128, b1 + l * HF, midb, NTOK, HF, D);
    // W2: midb -> y (f32)
    k_gemm_mfma<false, false><<<dim3(NTOK / 128, 1), 256, 0, stream>>>(
        midb, w2b + (size_t)l * 128 * 256, b2 + l * D, y, NTOK, D, HF);
    k_add_ln<<<dim3(NTOK / 4), 256, 0, stream>>>(x, xb, y, ln2s + l * D, ln2b + l * D);
  }

  // final projection: xb -> featb (bf16)
  k_gemm_mfma<false, true><<<dim3(NTOK / 128, 2), 256, 0, stream>>>(
      xb, wpb, bp, featb, NTOK, HF, D);
  k_proto_accum<<<dim3(NSUP / 256), 256, 0, stream>>>(featb, sup_out, sup_msk, psum, pcnt);
  k_proto_final<<<dim3(NC), 256, 0, stream>>>(psum, pcnt, protos);
  k_logits<<<dim3((SEQ * NC + 255) / 256), 256, 0, stream>>>(featb, protos, outp);
}

// Round 6
// 1051.463 us; speedup vs baseline: 4.6270x; 1.3019x over previous
//
#include <hip/hip_runtime.h>
#include <hip/hip_bf16.h>

constexpr int D    = 128;   // d_model
constexpr int HF   = 256;   // ffn / output dim
constexpr int NH   = 4;
constexpr int DH   = 32;
constexpr int NL   = 3;
constexpr int SEQ  = 1024;
constexpr int NB   = 65;    // 64 support + 1 query
constexpr int NTOK = NB * SEQ;   // 66560
constexpr int NSUP = 64 * SEQ;   // 65536
constexpr int NC   = 10;

using u16 = unsigned short;
using u32 = unsigned int;
typedef __bf16 bf16x8 __attribute__((ext_vector_type(8)));
typedef float  f32x4  __attribute__((ext_vector_type(4)));
typedef float  f32x16 __attribute__((ext_vector_type(16)));
typedef u16    u16x4  __attribute__((ext_vector_type(4)));
typedef u16    u16x8  __attribute__((ext_vector_type(8)));

static __device__ __forceinline__ u16 f2b(float f) {
  return __builtin_bit_cast(u16, (__bf16)f);
}
static __device__ __forceinline__ float b2f(u16 u) {
  return (float)__builtin_bit_cast(__bf16, u);
}

// ---------------- weight f32 -> bf16 ----------------
__global__ __launch_bounds__(256) void k_f2b(const float* __restrict__ in,
                                             u16* __restrict__ out, int n) {
  int i = blockIdx.x * 256 + threadIdx.x;
  if (i < n) out[i] = f2b(in[i]);
}

// ---------------- embedding (f32 x + bf16 xb) ----------------
__global__ __launch_bounds__(256) void k_embed(const int* __restrict__ sup,
                                               const int* __restrict__ qry,
                                               const float* __restrict__ emb,
                                               float* __restrict__ x,
                                               u16* __restrict__ xb) {
  int64_t i = (int64_t)blockIdx.x * 256 + threadIdx.x;
  int tok_i = (int)(i >> 7);
  int d = (int)(i & 127);
  int t = tok_i < NSUP ? sup[tok_i] : qry[tok_i - NSUP];
  float v = emb[t * D + d];
  x[i] = v;
  xb[i] = f2b(v);
}

// ---------------- MFMA GEMM: C[m,n] = sum_k A[m,k]*B[n,k] + bias[n] ----------------
template<bool RELU, bool BF16OUT>
__global__ __launch_bounds__(256) void k_gemm_mfma(const u16* __restrict__ A,
                                                   const u16* __restrict__ B,
                                                   const float* __restrict__ bias,
                                                   void* __restrict__ Cm,
                                                   int M, int N, int K) {
  const int tid = threadIdx.x;
  const int w = tid >> 6, l = tid & 63;
  const int g = l >> 4, c16 = l & 15;
  const int m0 = blockIdx.x * 128 + w * 32;
  const int n0 = blockIdx.y * 128;

  f32x4 acc[2][8] = {};
  const u16* a0p = A + (size_t)(m0 + c16) * K + g * 8;
  const u16* a1p = a0p + (size_t)16 * K;
  const u16* bp  = B + (size_t)(n0 + c16) * K + g * 8;

  for (int k = 0; k < K; k += 32) {
    bf16x8 a0 = *(const bf16x8*)(a0p + k);
    bf16x8 a1 = *(const bf16x8*)(a1p + k);
    #pragma unroll
    for (int nc = 0; nc < 8; ++nc) {
      bf16x8 b = *(const bf16x8*)(bp + (size_t)(nc * 16) * K + k);
      acc[0][nc] = __builtin_amdgcn_mfma_f32_16x16x32_bf16(a0, b, acc[0][nc], 0, 0, 0);
      acc[1][nc] = __builtin_amdgcn_mfma_f32_16x16x32_bf16(a1, b, acc[1][nc], 0, 0, 0);
    }
  }

  #pragma unroll
  for (int nc = 0; nc < 8; ++nc) {
    const int n_ = n0 + nc * 16 + c16;
    const float bs = bias[n_];
    #pragma unroll
    for (int mf = 0; mf < 2; ++mf)
      #pragma unroll
      for (int r = 0; r < 4; ++r) {
        const int m_ = m0 + mf * 16 + g * 4 + r;
        float v = acc[mf][nc][r] + bs;
        if (RELU) v = fmaxf(v, 0.f);
        if (BF16OUT) ((u16*)Cm)[(size_t)m_ * N + n_] = f2b(v);
        else         ((float*)Cm)[(size_t)m_ * N + n_] = v;
      }
  }
}

// ---------------- MFMA flash attention, swapped-operand 32x32 ----------------
// qkvb: bf16 [NTOK][384] = [q|k|v]; out: bf16 [NTOK][128].
// grid (qtile=32, bh=260); block 64 = ONE wave; wave owns 32 q rows.
// S^T = mfma32x32x16(K, Q): lane holds col q=l&31, key rows (r&3)+8*(r>>2)+4*(l>>5).
// O^T = mfma32x32x16(V^T, P^T): lane holds col q=l&31, dh rows same pattern.
__global__ __launch_bounds__(64) void k_attn_mfma(const u16* __restrict__ qkvb,
                                                  u16* __restrict__ out) {
  const int bh = blockIdx.y;
  const int b = bh >> 2, h = bh & 3;
  const int l = threadIdx.x;      // 0..63
  const int q5 = l & 31;
  const int hi = l >> 5;          // lane half
  const int qbase = blockIdx.x * 32;

  __shared__ u16 Vt[32 * 72];     // V^T: [dh][key], row stride 72 u16 (144B, 16B-aligned)
  u32* Vtw = (u32*)Vt;

  const size_t tok0 = (size_t)b * SEQ;
  constexpr float KSL = 0.25500446f;   // 1/sqrt(32) * log2(e)

  // Q B-fragments: lane holds Q[qbase+q5][dh = hi*8+j] (+16 for second half)
  const u16* qrow = qkvb + (tok0 + qbase + q5) * 384 + h * 32 + hi * 8;
  bf16x8 qf0 = *(const bf16x8*)(qrow);
  bf16x8 qf1 = *(const bf16x8*)(qrow + 16);

  f32x16 acc = {};                // O^T accumulator
  float m = -3.0e38f, lsum = 0.f;

  const u16* kbase = qkvb + tok0 * 384 + 128 + h * 32 + (size_t)q5 * 384 + hi * 8;
  const u16* vbase = qkvb + tok0 * 384 + 256 + h * 32 + hi * 16;
  const f32x16 z16 = {};

  for (int kt = 0; kt < SEQ; kt += 64) {
    // V stage: lane covers rows kt+2*q5, +1; cols hi*16..+16
    const u16* vr0 = vbase + (size_t)(kt + q5 * 2) * 384;
    const u16* vr1 = vr0 + 384;
    u16x8 a_lo = *(const u16x8*)(vr0);
    u16x8 a_hi = *(const u16x8*)(vr0 + 8);
    u16x8 b_lo = *(const u16x8*)(vr1);
    u16x8 b_hi = *(const u16x8*)(vr1 + 8);
    // K A-fragments: rows kt+q5 (+32), k-slot dh = hi*8+j (+16)
    const u16* kr = kbase + (size_t)kt * 384;
    bf16x8 k00 = *(const bf16x8*)(kr);
    bf16x8 k01 = *(const bf16x8*)(kr + 16);
    bf16x8 k10 = *(const bf16x8*)(kr + (size_t)32 * 384);
    bf16x8 k11 = *(const bf16x8*)(kr + (size_t)32 * 384 + 16);

    #pragma unroll
    for (int j = 0; j < 8; ++j) {
      Vtw[(hi * 16 + j) * 36 + q5]     = (u32)a_lo[j] | ((u32)b_lo[j] << 16);
      Vtw[(hi * 16 + 8 + j) * 36 + q5] = (u32)a_hi[j] | ((u32)b_hi[j] << 16);
    }
    __threadfence_block();
    __builtin_amdgcn_sched_barrier(0);

    // S^T: two 32-key subtiles
    f32x16 s0 = __builtin_amdgcn_mfma_f32_32x32x16_bf16(k00, qf0, z16, 0, 0, 0);
    s0 = __builtin_amdgcn_mfma_f32_32x32x16_bf16(k01, qf1, s0, 0, 0, 0);
    f32x16 s1 = __builtin_amdgcn_mfma_f32_32x32x16_bf16(k10, qf0, z16, 0, 0, 0);
    s1 = __builtin_amdgcn_mfma_f32_32x32x16_bf16(k11, qf1, s1, 0, 0, 0);

    // online softmax: lane owns q=q5; 32 scores in-lane, 32 in partner (l^32)
    float mx = s0[0];
    #pragma unroll
    for (int i = 1; i < 16; ++i) mx = fmaxf(mx, s0[i]);
    #pragma unroll
    for (int i = 0; i < 16; ++i) mx = fmaxf(mx, s1[i]);
    mx = fmaxf(mx, __shfl_xor(mx, 32));
    float mn = fmaxf(m, mx * KSL);
    float c0 = exp2f(m - mn);
    float p0[16], p1[16];
    float ps = 0.f;
    #pragma unroll
    for (int i = 0; i < 16; ++i) { p0[i] = exp2f(fmaf(s0[i], KSL, -mn)); ps += p0[i]; }
    #pragma unroll
    for (int i = 0; i < 16; ++i) { p1[i] = exp2f(fmaf(s1[i], KSL, -mn)); ps += p1[i]; }
    ps += __shfl_xor(ps, 32);
    lsum = lsum * c0 + ps;
    m = mn;
    #pragma unroll
    for (int i = 0; i < 16; ++i) acc[i] *= c0;

    // pack P pairs to bf16 words (key offsets o=(2m idx) per pattern)
    u32 pk0[8], pk1[8];
    #pragma unroll
    for (int mi = 0; mi < 8; ++mi) {
      pk0[mi] = (u32)f2b(p0[2 * mi]) | ((u32)f2b(p0[2 * mi + 1]) << 16);
      pk1[mi] = (u32)f2b(p1[2 * mi]) | ((u32)f2b(p1[2 * mi + 1]) << 16);
    }

    // PV: per subtile t (32 keys), per half hh (16 keys): exchange lane halves
    #pragma unroll
    for (int t = 0; t < 2; ++t) {
      #pragma unroll
      for (int hh = 0; hh < 2; ++hh) {
        u32 w0s = t ? pk1[4 * hh + 0] : pk0[4 * hh + 0];
        u32 w1s = t ? pk1[4 * hh + 1] : pk0[4 * hh + 1];
        u32 w2s = t ? pk1[4 * hh + 2] : pk0[4 * hh + 2];
        u32 w3s = t ? pk1[4 * hh + 3] : pk0[4 * hh + 3];
        u32 w0x = __shfl_xor(w0s, 32);
        u32 w1x = __shfl_xor(w1s, 32);
        u32 w2x = __shfl_xor(w2s, 32);
        u32 w3x = __shfl_xor(w3s, 32);
        union { u32 w[4]; bf16x8 v; } pf;
        pf.w[0] = hi ? w2x : w0s;
        pf.w[1] = hi ? w3x : w1s;
        pf.w[2] = hi ? w2s : w0x;
        pf.w[3] = hi ? w3s : w1x;
        bf16x8 vf = *(const bf16x8*)(Vt + (size_t)q5 * 72 + t * 32 + hh * 16 + hi * 8);
        acc = __builtin_amdgcn_mfma_f32_32x32x16_bf16(vf, pf.v, acc, 0, 0, 0);
      }
    }
    __threadfence_block();
    __builtin_amdgcn_sched_barrier(0);
  }

  // epilogue: lane writes row q=qbase+q5, dh = (r&3)+8*(r>>2)+4*hi
  float inv = 1.f / lsum;
  u16* orow = out + (tok0 + qbase + q5) * 128 + h * 32 + hi * 4;
  #pragma unroll
  for (int a = 0; a < 4; ++a) {
    u16x4 st;
    #pragma unroll
    for (int j = 0; j < 4; ++j) st[j] = f2b(acc[a * 4 + j] * inv);
    *(u16x4*)(orow + a * 8) = st;
  }
}

// ---------------- residual add + LayerNorm (x f32 in/out, xb bf16 out) ----------------
__global__ __launch_bounds__(256) void k_add_ln(float* __restrict__ x,
                                                u16* __restrict__ xb,
                                                const float* __restrict__ y,
                                                const float* __restrict__ gamma,
                                                const float* __restrict__ beta) {
  int row = blockIdx.x * 4 + (threadIdx.x >> 6);
  int lane = threadIdx.x & 63;
  float* xr = x + (size_t)row * D;
  const float* yr = y + (size_t)row * D;
  float2 v = *(float2*)(xr + lane * 2);
  float2 w = *(const float2*)(yr + lane * 2);
  float a = v.x + w.x, b = v.y + w.y;
  float sum = a + b;
  #pragma unroll
  for (int off = 32; off; off >>= 1) sum += __shfl_xor(sum, off);
  float mean = sum * (1.f / 128.f);
  float da = a - mean, db = b - mean;
  float vs = da * da + db * db;
  #pragma unroll
  for (int off = 32; off; off >>= 1) vs += __shfl_xor(vs, off);
  float inv = 1.f / sqrtf(vs * (1.f / 128.f) + 1e-5f);
  float2 o;
  o.x = da * inv * gamma[lane * 2 + 0] + beta[lane * 2 + 0];
  o.y = db * inv * gamma[lane * 2 + 1] + beta[lane * 2 + 1];
  *(float2*)(xr + lane * 2) = o;
  u32 pk = (u32)f2b(o.x) | ((u32)f2b(o.y) << 16);
  *(u32*)(xb + (size_t)row * D + lane * 2) = pk;
}

// ---------------- prototype accumulation (bf16 feat) ----------------
__global__ __launch_bounds__(256) void k_proto_accum(const u16* __restrict__ feat,
                                                     const int* __restrict__ cls,
                                                     const int* __restrict__ msk,
                                                     float* __restrict__ psum,
                                                     int* __restrict__ pcnt) {
  __shared__ float ls[NC][HF];
  __shared__ int lc[NC];
  int tid = threadIdx.x;
  #pragma unroll
  for (int c = 0; c < NC; ++c) ls[c][tid] = 0.f;
  if (tid < NC) lc[tid] = 0;
  __syncthreads();
  int t0 = blockIdx.x * 256;
  for (int t = t0; t < t0 + 256; ++t) {
    int cl = cls[t];
    int mk = msk[t];
    if (mk > 0 && cl < NC) {
      ls[cl][tid] += b2f(feat[(size_t)t * HF + tid]);
      if (tid == 0) lc[cl]++;
    }
  }
  __syncthreads();
  for (int c = 0; c < NC; ++c) atomicAdd(&psum[c * HF + tid], ls[c][tid]);
  if (tid < NC) atomicAdd(&pcnt[tid], lc[tid]);
}

__global__ void k_proto_final(const float* __restrict__ psum,
                              const int* __restrict__ pcnt,
                              float* __restrict__ protos) {
  int c = blockIdx.x, h = threadIdx.x;
  int n = pcnt[c];
  protos[c * HF + h] = (n > 0) ? psum[c * HF + h] / (float)n : 0.f;
}

// ---------------- logits ----------------
__global__ __launch_bounds__(256) void k_logits(const u16* __restrict__ feat,
                                                const float* __restrict__ protos,
                                                float* __restrict__ out) {
  int i = blockIdx.x * 256 + threadIdx.x;
  if (i >= SEQ * NC) return;
  int s = i / NC, c = i % NC;
  const u16* qf = feat + (size_t)(NSUP + s) * HF;
  const float* pr = protos + c * HF;
  float acc = 0.f;
  #pragma unroll 8
  for (int h = 0; h < HF; ++h) {
    float d = b2f(qf[h]) - pr[h];
    acc += d * d;
  }
  out[i] = -acc;
}

extern "C" void kernel_launch(void* const* d_in, const int* in_sizes, int n_in,
                              void* d_out, int out_size, void* d_ws, size_t ws_size,
                              hipStream_t stream) {
  const int*   sup_in  = (const int*)d_in[0];
  const int*   sup_out = (const int*)d_in[1];
  const int*   qry_in  = (const int*)d_in[2];
  const int*   sup_msk = (const int*)d_in[3];
  const float* emb     = (const float*)d_in[4];
  const float* Wqkv    = (const float*)d_in[5];
  const float* bqkv    = (const float*)d_in[6];
  const float* Wo      = (const float*)d_in[7];
  const float* bo      = (const float*)d_in[8];
  const float* ln1s    = (const float*)d_in[9];
  const float* ln1b    = (const float*)d_in[10];
  const float* W1      = (const float*)d_in[11];
  const float* b1      = (const float*)d_in[12];
  const float* W2      = (const float*)d_in[13];
  const float* b2      = (const float*)d_in[14];
  const float* ln2s    = (const float*)d_in[15];
  const float* ln2b    = (const float*)d_in[16];
  const float* Wp      = (const float*)d_in[17];
  const float* bp      = (const float*)d_in[18];

  float* ws = (float*)d_ws;
  float* x  = ws;
  float* y  = x + (size_t)NTOK * D;
  u16*   xb = (u16*)(y + (size_t)NTOK * D);
  u16*   yb = xb + (size_t)NTOK * D;
  u16*   U  = yb + (size_t)NTOK * D;            // NTOK*384 u16
  u16*   qkvb = U;
  u16*   midb = U;
  u16*   featb = U;
  u16*   wqkvb = U + (size_t)NTOK * 384;
  u16*   wob   = wqkvb + 3 * 384 * 128;
  u16*   w1b   = wob + 3 * 128 * 128;
  u16*   w2b   = w1b + 3 * 256 * 128;
  u16*   wpb   = w2b + 3 * 128 * 256;
  float* psum  = (float*)(((size_t)(wpb + 256 * 128) + 15) & ~(size_t)15);
  int*   pcnt  = (int*)(psum + NC * HF);
  float* protos = psum + NC * HF + 16;
  float* outp = (float*)d_out;

  hipMemsetAsync(psum, 0, NC * HF * sizeof(float) + 16 * sizeof(int), stream);

  k_f2b<<<dim3((3*384*128 + 255)/256), 256, 0, stream>>>(Wqkv, wqkvb, 3*384*128);
  k_f2b<<<dim3((3*128*128 + 255)/256), 256, 0, stream>>>(Wo,   wob,   3*128*128);
  k_f2b<<<dim3((3*256*128 + 255)/256), 256, 0, stream>>>(W1,   w1b,   3*256*128);
  k_f2b<<<dim3((3*128*256 + 255)/256), 256, 0, stream>>>(W2,   w2b,   3*128*256);
  k_f2b<<<dim3((256*128   + 255)/256), 256, 0, stream>>>(Wp,   wpb,   256*128);

  k_embed<<<dim3((NTOK * D) / 256), 256, 0, stream>>>(sup_in, qry_in, emb, x, xb);

  for (int l = 0; l < NL; ++l) {
    k_gemm_mfma<false, true><<<dim3(NTOK / 128, 3), 256, 0, stream>>>(
        xb, wqkvb + (size_t)l * 384 * 128, bqkv + l * 384, qkvb, NTOK, 384, D);
    k_attn_mfma<<<dim3(32, NB * NH), 64, 0, stream>>>(qkvb, yb);
    k_gemm_mfma<false, false><<<dim3(NTOK / 128, 1), 256, 0, stream>>>(
        yb, wob + (size_t)l * 128 * 128, bo + l * D, y, NTOK, D, D);
    k_add_ln<<<dim3(NTOK / 4), 256, 0, stream>>>(x, xb, y, ln1s + l * D, ln1b + l * D);
    k_gemm_mfma<true, true><<<dim3(NTOK / 128, 2), 256, 0, stream>>>(
        xb, w1b + (size_t)l * 256 * 128, b1 + l * HF, midb, NTOK, HF, D);
    k_gemm_mfma<false, false><<<dim3(NTOK / 128, 1), 256, 0, stream>>>(
        midb, w2b + (size_t)l * 128 * 256, b2 + l * D, y, NTOK, D, HF);
    k_add_ln<<<dim3(NTOK / 4), 256, 0, stream>>>(x, xb, y, ln2s + l * D, ln2b + l * D);
  }

  k_gemm_mfma<false, true><<<dim3(NTOK / 128, 2), 256, 0, stream>>>(
      xb, wpb, bp, featb, NTOK, HF, D);
  k_proto_accum<<<dim3(NSUP / 256), 256, 0, stream>>>(featb, sup_out, sup_msk, psum, pcnt);
  k_proto_final<<<dim3(NC), 256, 0, stream>>>(psum, pcnt, protos);
  k_logits<<<dim3((SEQ * NC + 255) / 256), 256, 0, stream>>>(featb, protos, outp);
}